// Round 4
// baseline (75.396 us; speedup 1.0000x reference)
//
#include <hip/hip_runtime.h>
#include <hip/hip_fp16.h>

// RoIAlign-3D: x[2,256,16,64,64] f32, rois[128,5] -> out[128,256,16,7,7] f32
// R4: precomputed factored tables (fp16 weights, byte offsets) staged in LDS;
// LP=66 (pair-bank (y+x) mod 16 kills dRow=8 conflicts); pk_fma math.
//
// ws layout (u32 words):
//  [0..895]      YOFF  : y00*264 (byte offset), entry = k*7+ph
//  [896..1791]   YW01  : half2(yw0, yw1)
//  [1792..2687]  YW23  : half2(yw2, 0)
//  [2688..3583]  XOFF  : xb2*8 (byte offset), entry = k*7+pw
//  [3584..4479]  XW01  : half2(w0, w1)   (shift + mask + 1/4 folded)
//  [4480..5375]  XW23  : half2(w2, w3)
//  [5376..5377]  nroi per image
//  [5378..5633]  roi list (128 per image)

#define LP   66
#define ROWB 264

typedef float v2f __attribute__((ext_vector_type(2)));

__device__ inline v2f h2f(unsigned u) {
    __half2 h = __builtin_bit_cast(__half2, u);
    float2 f = __half22float2(h);
    return v2f{f.x, f.y};
}

__global__ __launch_bounds__(128) void pooler_pre(const float* __restrict__ rois,
                                                  unsigned* __restrict__ wt) {
    __shared__ int sb[128];
    const int k = threadIdx.x;
    float x1 = rois[5 * k + 1] * 0.25f, y1 = rois[5 * k + 2] * 0.25f;
    float x2 = rois[5 * k + 3] * 0.25f, y2 = rois[5 * k + 4] * 0.25f;
    float bw = fmaxf(x2 - x1, 1.0f) * (1.0f / 14.0f);
    float bh = fmaxf(y2 - y1, 1.0f) * (1.0f / 14.0f);
    sb[k] = (int)rois[5 * k];
    for (int i = 0; i < 7; ++i) {
        int e = k * 7 + i;
        // ---- y: 2 samples -> 3-row weights (mask folded)
        float ys0 = fmaf((float)(2 * i) + 0.5f, bh, y1);
        float ys1 = ys0 + bh;
        float my0 = (ys0 >= -1.0f && ys0 <= 64.0f) ? 1.0f : 0.0f;
        float my1 = (ys1 >= -1.0f && ys1 <= 64.0f) ? 1.0f : 0.0f;
        float yc0 = fminf(fmaxf(ys0, 0.0f), 63.0f);
        float yc1 = fminf(fmaxf(ys1, 0.0f), 63.0f);
        int y00 = min((int)yc0, 62), y01 = min((int)yc1, 62);  // y01-y00 in {0,1}
        float ly0 = yc0 - (float)y00, ly1 = yc1 - (float)y01;
        float h0 = (1.0f - ly0) * my0, l0 = ly0 * my0;
        float h1 = (1.0f - ly1) * my1, l1 = ly1 * my1;
        bool dy = (y01 != y00);
        float yw0 = h0 + (dy ? 0.0f : h1);
        float yw1 = l0 + (dy ? h1 : l1);
        float yw2 = dy ? l1 : 0.0f;
        wt[e]        = (unsigned)(y00 * ROWB);
        wt[896 + e]  = __builtin_bit_cast(unsigned, __halves2half2(__float2half(yw0), __float2half(yw1)));
        wt[1792 + e] = __builtin_bit_cast(unsigned, __halves2half2(__float2half(yw2), __float2half(0.0f)));
        // ---- x: 2 samples -> 4-col window weights (mask, 1/4, shift folded)
        float xs0 = fmaf((float)(2 * i) + 0.5f, bw, x1);
        float xs1 = xs0 + bw;
        float mx0 = (xs0 >= -1.0f && xs0 <= 64.0f) ? 0.25f : 0.0f;
        float mx1 = (xs1 >= -1.0f && xs1 <= 64.0f) ? 0.25f : 0.0f;
        float xc0 = fminf(fmaxf(xs0, 0.0f), 63.0f);
        float xc1 = fminf(fmaxf(xs1, 0.0f), 63.0f);
        int x00 = min((int)xc0, 62), x01 = min((int)xc1, 62);  // x01-x00 in {0,1}
        float lx0 = xc0 - (float)x00, lx1 = xc1 - (float)x01;
        float a0 = (1.0f - lx0) * mx0, b0 = lx0 * mx0;
        float a1 = (1.0f - lx1) * mx1, b1 = lx1 * mx1;
        bool dx = (x01 != x00);
        float xw0 = a0 + (dx ? 0.0f : a1);
        float xw1 = b0 + (dx ? a1 : b1);
        float xw2 = dx ? b1 : 0.0f;
        bool odd = (x00 & 1);
        float w0 = odd ? 0.0f : xw0;
        float w1 = odd ? xw0 : xw1;
        float w2 = odd ? xw1 : xw2;
        float w3 = odd ? xw2 : 0.0f;
        wt[2688 + e] = (unsigned)((x00 >> 1) * 8);
        wt[3584 + e] = __builtin_bit_cast(unsigned, __halves2half2(__float2half(w0), __float2half(w1)));
        wt[4480 + e] = __builtin_bit_cast(unsigned, __halves2half2(__float2half(w2), __float2half(w3)));
    }
    __syncthreads();
    if (k == 0) {
        int c0 = 0, c1 = 0;
        for (int j = 0; j < 128; ++j) {
            if (sb[j] == 0) wt[5378 + c0++] = j;
            else            wt[5378 + 128 + c1++] = j;
        }
        wt[5376] = c0; wt[5377] = c1;
        for (int j = c0; j < 128; ++j) wt[5378 + j] = 0;
        for (int j = c1; j < 128; ++j) wt[5378 + 128 + j] = 0;
    }
}

__global__ __launch_bounds__(512, 8) void pooler_main(const float* __restrict__ x,
                                                      const unsigned* __restrict__ wt,
                                                      float* __restrict__ out) {
    __shared__ __align__(16) unsigned tab[5376];
    __shared__ __align__(16) float plane[65 * LP];
    __shared__ int rlist[128];
    __shared__ int snroi;

    const int tid = threadIdx.x;
    const int bid = blockIdx.x;
    const int b   = bid >> 12;

    // Stage the 64x64 plane (input read exactly once): float4 global reads,
    // 2x b64 LDS writes (264-byte rows are not 16B-aligned).
    const float4* src = (const float4*)(x + ((size_t)bid << 12));
    #pragma unroll
    for (int j = 0; j < 2; ++j) {
        int g = tid + j * 512;            // float4 index 0..1023
        float4 v = src[g];
        float* d = &plane[(g >> 4) * LP + ((g & 15) << 2)];
        ((float2*)d)[0] = make_float2(v.x, v.y);
        ((float2*)d)[1] = make_float2(v.z, v.w);
    }
    // Zero pads: cols 64,65 of rows 0..64 and pad row 64 (weights there are 0).
    if (tid < 98) {
        if (tid < 65) { plane[tid * LP + 64] = 0.f; plane[tid * LP + 65] = 0.f; }
        else { int c2 = (tid - 65) * 2; plane[64 * LP + c2] = 0.f; plane[64 * LP + c2 + 1] = 0.f; }
    }
    // Stage tables + roi list.
    #pragma unroll
    for (int j = 0; j < 3; ++j) {
        int g = tid + j * 512;
        if (g < 1344) ((float4*)tab)[g] = ((const float4*)wt)[g];
    }
    if (tid < 128) rlist[tid] = (int)wt[5378 + (b << 7) + tid];
    if (tid == 0)  snroi = (int)wt[5376 + b];
    __syncthreads();

    const int pl = bid & 4095;
    const int ntask = snroi * 7;
    for (int task = tid; task < ntask; task += 512) {
        int r  = task / 7;
        int ph = task - r * 7;
        int k  = rlist[r];
        int ye = k * 7 + ph;
        unsigned yoff = tab[ye];
        v2f yab = h2f(tab[896 + ye]);     // yw0, yw1
        v2f ycd = h2f(tab[1792 + ye]);    // yw2, 0
        const char* prow = (const char*)plane + yoff;
        float* po = out + ((size_t)((k << 12) | pl)) * 49 + ph * 7;
        #pragma unroll
        for (int pw = 0; pw < 7; ++pw) {
            int xe = k * 7 + pw;
            const char* p = prow + tab[2688 + xe];
            v2f w01 = h2f(tab[3584 + xe]);
            v2f w23 = h2f(tab[4480 + xe]);
            v2f r0a = *(const v2f*)p,              r0b = *(const v2f*)(p + 8);
            v2f r1a = *(const v2f*)(p + ROWB),     r1b = *(const v2f*)(p + ROWB + 8);
            v2f r2a = *(const v2f*)(p + 2 * ROWB), r2b = *(const v2f*)(p + 2 * ROWB + 8);
            v2f s0 = __builtin_elementwise_fma(r0b, w23, r0a * w01);
            v2f s1 = __builtin_elementwise_fma(r1b, w23, r1a * w01);
            v2f s2 = __builtin_elementwise_fma(r2b, w23, r2a * w01);
            v2f acc = s0 * v2f{yab.x, yab.x};
            acc = __builtin_elementwise_fma(s1, v2f{yab.y, yab.y}, acc);
            acc = __builtin_elementwise_fma(s2, v2f{ycd.x, ycd.x}, acc);
            po[pw] = acc.x + acc.y;
        }
    }
}

extern "C" void kernel_launch(void* const* d_in, const int* in_sizes, int n_in,
                              void* d_out, int out_size, void* d_ws, size_t ws_size,
                              hipStream_t stream) {
    const float* x    = (const float*)d_in[0];
    const float* rois = (const float*)d_in[1];
    float* out = (float*)d_out;
    unsigned* wt = (unsigned*)d_ws;
    pooler_pre<<<1, 128, 0, stream>>>(rois, wt);
    pooler_main<<<2 * 256 * 16, 512, 0, stream>>>(x, wt, out);
}